// Round 4
// baseline (131.315 us; speedup 1.0000x reference)
//
#include <hip/hip_runtime.h>

#define B_SZ 8192
#define C_SZ 1024
#define NCLS 100
#define INV_T 0.25f
#define MAX_ITEMS 65536

typedef unsigned int uint32;

using bf16x8 = __attribute__((ext_vector_type(8))) short;
using f32x16 = __attribute__((ext_vector_type(16))) float;

// round-to-nearest-even fp32 -> bf16 (inputs are positive, finite)
__device__ __forceinline__ unsigned short f2bf(float f) {
    uint32 u = __float_as_uint(f);
    u = u + 0x7fffu + ((u >> 16) & 1u);
    return (unsigned short)(u >> 16);
}

// Block 0: prep (zero accum/done, bucket rows by label via LDS atomics, build the
// 32x32-tile item table). Blocks 1..B_SZ: row softmax(x/T)+1e-8 -> bf16 probs and
// t[row] = mean(p*log p). Prep is independent of the row work and hides under it.
__global__ __launch_bounds__(256) void softmax_prep_kernel(
        const float* __restrict__ x, const int* __restrict__ target,
        uint32* __restrict__ probs_bf, float* __restrict__ t,
        int* __restrict__ counts, int* __restrict__ lists,
        int* __restrict__ items, int* __restrict__ nitems,
        float* __restrict__ accum, int* __restrict__ done_ctr) {
    int tid = threadIdx.x;

    if (blockIdx.x == 0) {
        __shared__ int cnt[NCLS];
        __shared__ int tbase[NCLS];
        if (tid < NCLS) cnt[tid] = 0;
        if (tid == 0) { accum[0] = 0.0f; done_ctr[0] = 0; }
        __syncthreads();
        #pragma unroll 4
        for (int i = 0; i < B_SZ / 256; i++) {
            int r = i * 256 + tid;
            int lbl = target[r];
            if (lbl < 0) lbl = 0;
            if (lbl >= NCLS) lbl = NCLS - 1;   // defensive: keep in-bounds
            int slot = atomicAdd(&cnt[lbl], 1);
            lists[lbl * B_SZ + slot] = r;
        }
        __syncthreads();
        if (tid < NCLS) counts[tid] = cnt[tid];
        if (tid == 0) {
            int tot = 0;
            for (int k = 0; k < NCLS; k++) {
                int nt = (cnt[k] + 31) >> 5;
                tbase[k] = tot;
                tot += nt * nt;
            }
            nitems[0] = tot;
        }
        __syncthreads();
        if (tid < NCLS) {
            int nt = (cnt[tid] + 31) >> 5;
            int base = tbase[tid];
            int z = 0;
            for (int a = 0; a < nt; a++)
                for (int b = 0; b < nt; b++)
                    items[base + z++] = tid | (a << 8) | (b << 20);
        }
        return;
    }

    int row = blockIdx.x - 1;
    const float4* xr = (const float4*)(x + (size_t)row * C_SZ);
    float4 v = xr[tid];
    v.x *= INV_T; v.y *= INV_T; v.z *= INV_T; v.w *= INV_T;

    __shared__ float red[12];
    int wid = tid >> 6;

    float m = fmaxf(fmaxf(v.x, v.y), fmaxf(v.z, v.w));
    #pragma unroll
    for (int o = 32; o >= 1; o >>= 1) m = fmaxf(m, __shfl_xor(m, o, 64));
    if ((tid & 63) == 0) red[wid] = m;
    __syncthreads();
    m = fmaxf(fmaxf(red[0], red[1]), fmaxf(red[2], red[3]));

    float4 e;
    e.x = __expf(v.x - m); e.y = __expf(v.y - m);
    e.z = __expf(v.z - m); e.w = __expf(v.w - m);
    float s = (e.x + e.y) + (e.z + e.w);
    #pragma unroll
    for (int o = 32; o >= 1; o >>= 1) s += __shfl_xor(s, o, 64);
    if ((tid & 63) == 0) red[4 + wid] = s;
    __syncthreads();
    float Z = (red[4] + red[5]) + (red[6] + red[7]);
    float rZ = 1.0f / Z;

    float4 p;
    p.x = e.x * rZ + 1e-8f; p.y = e.y * rZ + 1e-8f;
    p.z = e.z * rZ + 1e-8f; p.w = e.w * rZ + 1e-8f;

    uint2 packed;
    packed.x = ((uint32)f2bf(p.y) << 16) | (uint32)f2bf(p.x);
    packed.y = ((uint32)f2bf(p.w) << 16) | (uint32)f2bf(p.z);
    ((uint2*)(probs_bf + (size_t)row * (C_SZ / 2)))[tid] = packed;

    float pl = p.x * __logf(p.x) + p.y * __logf(p.y) +
               p.z * __logf(p.z) + p.w * __logf(p.w);
    #pragma unroll
    for (int o = 32; o >= 1; o >>= 1) pl += __shfl_xor(pl, o, 64);
    if ((tid & 63) == 0) red[8 + wid] = pl;
    __syncthreads();
    if (tid == 0)
        t[row] = ((red[8] + red[9]) + (red[10] + red[11])) * (1.0f / C_SZ);
}

// 4 waves per 32x32 output tile, K split 4 ways (256 cols each). Per wave:
// all 32 fragment loads (16B/lane, exactly the mfma_f32_32x32x16_bf16 A/B
// layout) are batched into static register arrays BEFORE the 16 MFMAs --
// round-3 showed the compiler will NOT hoist loads across the serial MFMA
// chain on its own (VGPR stayed 56, 52us of serialized latency). Source-level
// batching forces ~32 loads in flight; K-split gives ~3600 waves of TLP.
// Cross-wave reduce via LDS (lane-stride-4 = conflict-free), wave 0 epilogue.
__global__ __launch_bounds__(256, 1) void pair_kernel(
        const char* __restrict__ probs, const float* __restrict__ t,
        const int* __restrict__ counts, const int* __restrict__ lists,
        const int* __restrict__ nitems, const int* __restrict__ items,
        float* __restrict__ accum, int* __restrict__ done_ctr,
        float* __restrict__ out) {
    __shared__ float racc[4][16][64];    // [wave][reg][lane], 16 KB
    int tid = threadIdx.x;
    int wv = tid >> 6;
    int lane = tid & 63;
    int l = lane & 31;
    int h = lane >> 5;
    int NI = nitems[0];
    if (NI > MAX_ITEMS) NI = MAX_ITEMS;          // defensive: never walk garbage
    float lacc = 0.0f;

    for (int it = blockIdx.x; it < NI; it += (int)gridDim.x) {
        int pk = items[it];
        int k = pk & 255;
        if (k >= NCLS) continue;                 // defensive
        int ti = (pk >> 8) & 0xfff;
        int tj = pk >> 20;
        int m = counts[k];
        if (m < 1) continue;                     // defensive
        if (m > B_SZ) m = B_SZ;

        int ia = ti * 32 + l; if (ia > m - 1) ia = m - 1;   // clamp; masked below
        int ja = tj * 32 + l; if (ja > m - 1) ja = m - 1;
        int ra = lists[k * B_SZ + ia] & (B_SZ - 1);          // defensive mask
        int rb = lists[k * B_SZ + ja] & (B_SZ - 1);
        // wave wv covers global k-steps [wv*16, wv*16+16) -> byte offset wv*512
        const char* rowA = probs + (size_t)ra * (C_SZ * 2) + h * 16 + wv * 512;
        const char* rowB = probs + (size_t)rb * (C_SZ * 2) + h * 16 + wv * 512;
        float tjv = t[rb];    // hoisted into the load batch (epilogue use)

        bf16x8 a[16], b[16];
        #pragma unroll
        for (int i = 0; i < 16; i++) {
            a[i] = *(const bf16x8*)(rowA + i * 32);
            b[i] = *(const bf16x8*)(rowB + i * 32);
        }
        f32x16 acc = {};
        #pragma unroll
        for (int i = 0; i < 16; i++)
            acc = __builtin_amdgcn_mfma_f32_32x32x16_bf16(a[i], b[i], acc, 0, 0, 0);

        __syncthreads();      // racc free from previous item
        #pragma unroll
        for (int g = 0; g < 16; g++) racc[wv][g][lane] = acc[g];
        __syncthreads();

        if (wv == 0) {
            // D layout: col = lane&31 (B/tj side), row = (g&3)+8*(g>>2)+4*h (A/ti)
            int jl = tj * 32 + l;
            bool jv = jl < m;
            float local = 0.0f;
            #pragma unroll
            for (int g = 0; g < 16; g++) {
                float s = (racc[0][g][lane] + racc[1][g][lane]) +
                          (racc[2][g][lane] + racc[3][g][lane]);
                int rowloc = (g & 3) + 8 * (g >> 2) + 4 * h;
                int il = ti * 32 + rowloc;
                if (jv && il < m && il != jl) {
                    float kl = tjv - s * (1.0f / C_SZ);
                    local += kl * kl;
                }
            }
            lacc += local;
        }
    }

    if (wv == 0) {
        #pragma unroll
        for (int o = 32; o >= 1; o >>= 1) lacc += __shfl_xor(lacc, o, 64);
        if (lane == 0) {
            atomicAdd(accum, lacc);
            __threadfence();
            if (atomicAdd(done_ctr, 1) == (int)gridDim.x - 1) {
                __threadfence();
                out[0] = atomicAdd(accum, 0.0f) * (1.0f / B_SZ);
            }
        }
    }
}

extern "C" void kernel_launch(void* const* d_in, const int* in_sizes, int n_in,
                              void* d_out, int out_size, void* d_ws, size_t ws_size,
                              hipStream_t stream) {
    const float* x = (const float*)d_in[0];
    const int* target = (const int*)d_in[1];
    float* out = (float*)d_out;

    char* ws = (char*)d_ws;
    uint32* probs_bf = (uint32*)ws;                                   // 16 MB (B*C bf16)
    char* p = ws + (size_t)B_SZ * C_SZ * 2;
    float* t = (float*)p;            p += B_SZ * 4;                   // 32 KB
    int* counts = (int*)p;           p += 128 * 4;                    // 512 B
    int* nitems = (int*)p;           p += 16;                         // 4 B (+pad)
    int* lists = (int*)p;            p += (size_t)NCLS * B_SZ * 4;    // 3.2 MB
    int* items = (int*)p;            p += MAX_ITEMS * 4;              // 256 KB
    float* accum = (float*)p;        p += 16;                         // 4 B (+pad)
    int* done_ctr = (int*)p;                                          // 4 B

    softmax_prep_kernel<<<B_SZ + 1, 256, 0, stream>>>(x, target, probs_bf, t,
                                                      counts, lists, items, nitems,
                                                      accum, done_ctr);
    pair_kernel<<<1024, 256, 0, stream>>>((const char*)probs_bf, t, counts, lists,
                                          nitems, items, accum, done_ctr, out);
}

// Round 5
// 104.441 us; speedup vs baseline: 1.2573x; 1.2573x over previous
//
#include <hip/hip_runtime.h>

#define B_SZ 8192
#define C_SZ 1024
#define NCLS 100
#define INV_T 0.25f
#define MAX_ITEMS 65536
#define GRP 64            // rows per group (2 MFMA tiles)
#define NCH 8             // K chunks of 128 cols (256 B/row)

typedef unsigned int uint32;

using bf16x8 = __attribute__((ext_vector_type(8))) short;
using f32x16 = __attribute__((ext_vector_type(16))) float;

// round-to-nearest-even fp32 -> bf16 (inputs are positive, finite)
__device__ __forceinline__ unsigned short f2bf(float f) {
    uint32 u = __float_as_uint(f);
    u = u + 0x7fffu + ((u >> 16) & 1u);
    return (unsigned short)(u >> 16);
}

__device__ __forceinline__ void gload16_lds(const void* g, void* l) {
    __builtin_amdgcn_global_load_lds(
        (const __attribute__((address_space(1))) uint32*)g,
        (__attribute__((address_space(3))) uint32*)l, 16, 0, 0);
}

// Block 0: prep (zero accum/done, bucket rows by label via LDS atomics, build the
// (class, gi, gj) 64-row group-pair item table). Blocks 1..B_SZ: row softmax.
__global__ __launch_bounds__(256) void softmax_prep_kernel(
        const float* __restrict__ x, const int* __restrict__ target,
        uint32* __restrict__ probs_bf, float* __restrict__ t,
        int* __restrict__ counts, int* __restrict__ lists,
        int* __restrict__ items, int* __restrict__ nitems,
        float* __restrict__ accum, int* __restrict__ done_ctr) {
    int tid = threadIdx.x;

    if (blockIdx.x == 0) {
        __shared__ int cnt[NCLS];
        __shared__ int tbase[NCLS];
        if (tid < NCLS) cnt[tid] = 0;
        if (tid == 0) { accum[0] = 0.0f; done_ctr[0] = 0; }
        __syncthreads();
        #pragma unroll 4
        for (int i = 0; i < B_SZ / 256; i++) {
            int r = i * 256 + tid;
            int lbl = target[r];
            if (lbl < 0) lbl = 0;
            if (lbl >= NCLS) lbl = NCLS - 1;   // defensive: keep in-bounds
            int slot = atomicAdd(&cnt[lbl], 1);
            lists[lbl * B_SZ + slot] = r;
        }
        __syncthreads();
        if (tid < NCLS) counts[tid] = cnt[tid];
        if (tid == 0) {
            int tot = 0;
            for (int k = 0; k < NCLS; k++) {
                int ng = (cnt[k] + GRP - 1) / GRP;
                tbase[k] = tot;
                tot += ng * ng;
            }
            nitems[0] = tot;
        }
        __syncthreads();
        if (tid < NCLS) {
            int ng = (cnt[tid] + GRP - 1) / GRP;
            int base = tbase[tid];
            int z = 0;
            for (int a = 0; a < ng; a++)
                for (int b = 0; b < ng; b++)
                    items[base + z++] = tid | (a << 8) | (b << 20);
        }
        return;
    }

    int row = blockIdx.x - 1;
    const float4* xr = (const float4*)(x + (size_t)row * C_SZ);
    float4 v = xr[tid];
    v.x *= INV_T; v.y *= INV_T; v.z *= INV_T; v.w *= INV_T;

    __shared__ float red[12];
    int wid = tid >> 6;

    float m = fmaxf(fmaxf(v.x, v.y), fmaxf(v.z, v.w));
    #pragma unroll
    for (int o = 32; o >= 1; o >>= 1) m = fmaxf(m, __shfl_xor(m, o, 64));
    if ((tid & 63) == 0) red[wid] = m;
    __syncthreads();
    m = fmaxf(fmaxf(red[0], red[1]), fmaxf(red[2], red[3]));

    float4 e;
    e.x = __expf(v.x - m); e.y = __expf(v.y - m);
    e.z = __expf(v.z - m); e.w = __expf(v.w - m);
    float s = (e.x + e.y) + (e.z + e.w);
    #pragma unroll
    for (int o = 32; o >= 1; o >>= 1) s += __shfl_xor(s, o, 64);
    if ((tid & 63) == 0) red[4 + wid] = s;
    __syncthreads();
    float Z = (red[4] + red[5]) + (red[6] + red[7]);
    float rZ = 1.0f / Z;

    float4 p;
    p.x = e.x * rZ + 1e-8f; p.y = e.y * rZ + 1e-8f;
    p.z = e.z * rZ + 1e-8f; p.w = e.w * rZ + 1e-8f;

    uint2 packed;
    packed.x = ((uint32)f2bf(p.y) << 16) | (uint32)f2bf(p.x);
    packed.y = ((uint32)f2bf(p.w) << 16) | (uint32)f2bf(p.z);
    ((uint2*)(probs_bf + (size_t)row * (C_SZ / 2)))[tid] = packed;

    float pl = p.x * __logf(p.x) + p.y * __logf(p.y) +
               p.z * __logf(p.z) + p.w * __logf(p.w);
    #pragma unroll
    for (int o = 32; o >= 1; o >>= 1) pl += __shfl_xor(pl, o, 64);
    if ((tid & 63) == 0) red[8 + wid] = pl;
    __syncthreads();
    if (tid == 0)
        t[row] = ((red[8] + red[9]) + (red[10] + red[11])) * (1.0f / C_SZ);
}

// One 256-thread block per (class, gi, gj) 64-row group pair; 4 waves = 4 32x32
// tiles. Rounds 2-4 showed direct fragment loads are killed by 32-way address
// divergence (each load instr touches 32 cache lines -> request-rate bound at
// ~53us regardless of ILP/TLP). Here the strips are staged COALESCED (row-
// contiguous 16B/lane) via async global_load_lds into double-buffered LDS, with
// the bank-conflict XOR applied on the pre-swizzled global source (linear LDS
// dest, rule 21) and mirrored on the ds_read_b128 fragment reads. 2-phase
// pipeline: issue next chunk's stages, compute current, one barrier per chunk.
// Diagonal items (gi==gj) stage one strip only.
__global__ __launch_bounds__(256, 1) void pair_kernel(
        const char* __restrict__ probs, const float* __restrict__ t,
        const int* __restrict__ counts, const int* __restrict__ lists,
        const int* __restrict__ nitems, const int* __restrict__ items,
        float* __restrict__ accum, int* __restrict__ done_ctr,
        float* __restrict__ out) {
    __shared__ uint32 sA[2 * GRP * 64];   // 2 bufs x 64 rows x 256 B = 32 KB
    __shared__ uint32 sB[2 * GRP * 64];   // 32 KB
    __shared__ int s_ridA[GRP];
    __shared__ int s_ridB[GRP];
    __shared__ float s_tB[GRP];
    __shared__ float s_wsum[4];

    int tid = threadIdx.x;
    int wv = tid >> 6;
    int lane = tid & 63;
    int l = lane & 31;
    int h = lane >> 5;
    int NI = nitems[0];
    if (NI > MAX_ITEMS) NI = MAX_ITEMS;          // defensive
    float lacc = 0.0f;

    for (int it = blockIdx.x; it < NI; it += (int)gridDim.x) {
        int pk = items[it];
        int k = pk & 255;
        if (k >= NCLS) continue;                 // defensive
        int gi = (pk >> 8) & 0xfff;
        int gj = pk >> 20;
        int m = counts[k];
        if (m < 1) continue;                     // defensive
        if (m > B_SZ) m = B_SZ;
        bool same = (gi == gj);

        __syncthreads();   // previous item fully done with LDS
        if (tid < GRP) {
            int which = gi * GRP + tid; if (which > m - 1) which = m - 1;
            s_ridA[tid] = lists[k * B_SZ + which] & (B_SZ - 1);
        } else if (tid < 2 * GRP) {
            int r = tid - GRP;
            int which = gj * GRP + r; if (which > m - 1) which = m - 1;
            int rid = lists[k * B_SZ + which] & (B_SZ - 1);
            s_ridB[r] = rid;
            s_tB[r] = t[rid];
        }
        __syncthreads();

        int rowsA = m - gi * GRP; if (rowsA > GRP) rowsA = GRP;
        int rowsB = m - gj * GRP; if (rowsB > GRP) rowsB = GRP;
        int ntA = (rowsA + 31) >> 5;
        int ntB = (rowsB + 31) >> 5;
        int npairs = ntA * ntB;
        int ti = wv / ntB;
        int tj = wv % ntB;

        // ---- stage macro: chunk ch -> buffer bb (async, vmcnt-pending) ----
        #define STAGE(ch, bb)                                                     \
            _Pragma("unroll")                                                     \
            for (int rr = 0; rr < 8; rr++) {                                      \
                if (!(same && rr >= 4)) {                                         \
                    int slot = rr * 256 + tid;                                    \
                    int row = (slot >> 4) & 63;                                   \
                    int c16 = slot & 15;                                          \
                    int rid = (rr >= 4) ? s_ridB[row] : s_ridA[row];              \
                    const char* gp = probs + ((size_t)rid << 11) + ((ch) << 8) +  \
                                     ((c16 ^ (row & 7)) << 4);                    \
                    uint32* lp = ((rr >= 4) ? sB : sA) + (bb) * (GRP * 64) +      \
                                 (((rr & 3) * 256 + wv * 64) << 2);               \
                    gload16_lds(gp, lp);                                          \
                }                                                                 \
            }

        STAGE(0, 0);
        __syncthreads();   // drain vmcnt -> buf0 ready

        f32x16 acc = {};
        int bb = 0;
        #pragma unroll 1
        for (int ch = 0; ch < NCH; ch++) {
            if (ch + 1 < NCH) STAGE(ch + 1, bb ^ 1);
            if (wv < npairs) {
                const uint32* pA = sA + bb * (GRP * 64);
                const uint32* pB = (same ? sA : sB) + bb * (GRP * 64);
                #pragma unroll
                for (int ks = 0; ks < 8; ks++) {
                    int ra = ti * 32 + l;
                    int ca = (ks * 2 + h) ^ (ra & 7);
                    bf16x8 av = *(const bf16x8*)(pA + ra * 64 + ca * 4);
                    int rb = tj * 32 + l;
                    int cb = (ks * 2 + h) ^ (rb & 7);
                    bf16x8 bv = *(const bf16x8*)(pB + rb * 64 + cb * 4);
                    acc = __builtin_amdgcn_mfma_f32_32x32x16_bf16(av, bv, acc, 0, 0, 0);
                }
            }
            __syncthreads();   // all waves done with buf[bb]; stage of bb^1 drained
            bb ^= 1;
        }
        #undef STAGE

        // epilogue: D col = lane&31 (B/tj side), row = (g&3)+8*(g>>2)+4*h (A/ti)
        if (wv < npairs) {
            int jloc = tj * 32 + l;
            int jl = gj * GRP + jloc;
            bool jv = jl < m;
            float tjv = s_tB[jloc];
            float local = 0.0f;
            #pragma unroll
            for (int g = 0; g < 16; g++) {
                int rowloc = (g & 3) + 8 * (g >> 2) + 4 * h;
                int il = gi * GRP + ti * 32 + rowloc;
                if (jv && il < m && il != jl) {
                    float kl = tjv - acc[g] * (1.0f / C_SZ);
                    local += kl * kl;
                }
            }
            lacc += local;
        }
    }

    #pragma unroll
    for (int o = 32; o >= 1; o >>= 1) lacc += __shfl_xor(lacc, o, 64);
    __syncthreads();
    if (lane == 0) s_wsum[wv] = lacc;
    __syncthreads();
    if (tid == 0) {
        float tot = (s_wsum[0] + s_wsum[1]) + (s_wsum[2] + s_wsum[3]);
        atomicAdd(accum, tot);
        __threadfence();
        if (atomicAdd(done_ctr, 1) == (int)gridDim.x - 1) {
            __threadfence();
            out[0] = atomicAdd(accum, 0.0f) * (1.0f / B_SZ);
        }
    }
}

extern "C" void kernel_launch(void* const* d_in, const int* in_sizes, int n_in,
                              void* d_out, int out_size, void* d_ws, size_t ws_size,
                              hipStream_t stream) {
    const float* x = (const float*)d_in[0];
    const int* target = (const int*)d_in[1];
    float* out = (float*)d_out;

    char* ws = (char*)d_ws;
    uint32* probs_bf = (uint32*)ws;                                   // 16 MB (B*C bf16)
    char* p = ws + (size_t)B_SZ * C_SZ * 2;
    float* t = (float*)p;            p += B_SZ * 4;                   // 32 KB
    int* counts = (int*)p;           p += 128 * 4;                    // 512 B
    int* nitems = (int*)p;           p += 16;                         // 4 B (+pad)
    int* lists = (int*)p;            p += (size_t)NCLS * B_SZ * 4;    // 3.2 MB
    int* items = (int*)p;            p += MAX_ITEMS * 4;              // 256 KB
    float* accum = (float*)p;        p += 16;                         // 4 B (+pad)
    int* done_ctr = (int*)p;                                          // 4 B

    softmax_prep_kernel<<<B_SZ + 1, 256, 0, stream>>>(x, target, probs_bf, t,
                                                      counts, lists, items, nitems,
                                                      accum, done_ctr);
    pair_kernel<<<512, 256, 0, stream>>>((const char*)probs_bf, t, counts, lists,
                                         nitems, items, accum, done_ctr, out);
}